// Round 1
// baseline (235.440 us; speedup 1.0000x reference)
//
#include <hip/hip_runtime.h>

// Correlation layer: out[b, (dy+4)*9+(dx+4), y, x] =
//   (1/C) * sum_c first[b,c,y,x] * second[b,c,y+dy,x+dx], zero-padded.
//
// Strategy: dy split into 3 groups of 3 across gridDim.z (acc fits VGPRs:
// 3*9*4 = 108). Inputs re-read 3x but L3 (256 MB) absorbs it.
// Per block: 32x16 spatial tile, 128 threads (8 tx * 16 ty), 4 px/thread.
// Second staged per-channel in LDS (18 x 48 fp32, pitch 48), double-buffered.

constexpr int Bn = 8;
constexpr int Cn = 128;
constexpr int Hn = 96;
constexpr int Wn = 160;
constexpr int CHS = Hn * Wn;          // 15360 elements per channel plane

constexpr int TW = 32, TH = 16;       // spatial tile
constexpr int NT = 128;               // threads per block (8 x 16)
constexpr int HALO_ROWS = TH + 2;     // 18 rows (3 dy in group + 16 rows - 1)
constexpr int HALO_C4 = 12;           // float4 chunks per row (48 floats, origin x0-8)
constexpr int PITCH = 48;             // LDS words per row
constexpr int SLOTS = HALO_ROWS * HALO_C4;  // 216 float4 staging slots

__global__ __launch_bounds__(NT, 2)
void corr3(const float* __restrict__ first,
           const float* __restrict__ second,
           float* __restrict__ out)
{
    __shared__ float lds[2][HALO_ROWS * PITCH];   // 2 x 864 floats = 6.9 KB

    const int tid = threadIdx.x;
    const int tx  = tid & 7;          // 0..7, 4 px each -> 32 px
    const int ty  = tid >> 3;         // 0..15
    const int x0  = blockIdx.x * TW;
    const int y0  = blockIdx.y * TH;
    const int b   = blockIdx.z / 3;
    const int g   = blockIdx.z % 3;   // dy group: dy' = 3g + d, d in 0..2
    const int row0 = y0 + 3 * g - 4;  // global row of LDS row 0

    // Staging descriptors (static per thread): slot e -> (row, chunk)
    const int e0 = tid, e1 = tid + NT;
    const int r0 = e0 / HALO_C4, c40 = e0 % HALO_C4;
    const int r1 = e1 / HALO_C4, c41 = e1 % HALO_C4;
    const int gy0 = row0 + r0, gy1 = row0 + r1;
    const int gx0 = x0 - 8 + c40 * 4, gx1 = x0 - 8 + c41 * 4;
    const bool s1ok = (e1 < SLOTS);
    const bool v0 = (gy0 >= 0) & (gy0 < Hn) & (gx0 >= 0) & (gx0 < Wn);
    const bool v1 = s1ok & (gy1 >= 0) & (gy1 < Hn) & (gx1 >= 0) & (gx1 < Wn);
    const int go0 = gy0 * Wn + gx0;   // only used when valid
    const int go1 = gy1 * Wn + gx1;
    const int lo0 = r0 * PITCH + c40 * 4;
    const int lo1 = r1 * PITCH + c41 * 4;

    const float* secb = second + (size_t)b * Cn * CHS;
    const float* fb   = first  + (size_t)b * Cn * CHS + (y0 + ty) * Wn + x0 + tx * 4;

    float acc[3][9][4] = {};

    // ---- stage channel 0 ----
    {
        float4 a0 = make_float4(0.f, 0.f, 0.f, 0.f);
        float4 a1 = make_float4(0.f, 0.f, 0.f, 0.f);
        if (v0) a0 = *(const float4*)(secb + go0);
        if (v1) a1 = *(const float4*)(secb + go1);
        *(float4*)&lds[0][lo0] = a0;
        if (s1ok) *(float4*)&lds[0][lo1] = a1;
    }
    __syncthreads();

    #pragma unroll 1
    for (int c = 0; c < Cn; ++c) {
        const int cur = c & 1;

        // prefetch next channel into registers (hidden behind compute)
        float4 n0 = make_float4(0.f, 0.f, 0.f, 0.f);
        float4 n1 = make_float4(0.f, 0.f, 0.f, 0.f);
        const bool hn = (c + 1 < Cn);
        if (hn) {
            const float* sp = secb + (c + 1) * CHS;
            if (v0) n0 = *(const float4*)(sp + go0);
            if (v1) n1 = *(const float4*)(sp + go1);
        }

        float4 fv = *(const float4*)(fb + c * CHS);
        float fa[4] = {fv.x, fv.y, fv.z, fv.w};

        #pragma unroll
        for (int d = 0; d < 3; ++d) {
            // second row y+dy'-4 = row0 + ty + d; cols x0-4+tx*4 .. +11
            // LDS col (halo origin x0-8): tx*4+4 .. tx*4+15 (16B aligned)
            const float* rp = &lds[cur][(ty + d) * PITCH + tx * 4 + 4];
            float4 w0 = *(const float4*)(rp + 0);
            float4 w1 = *(const float4*)(rp + 4);
            float4 w2 = *(const float4*)(rp + 8);
            float w[12] = {w0.x, w0.y, w0.z, w0.w,
                           w1.x, w1.y, w1.z, w1.w,
                           w2.x, w2.y, w2.z, w2.w};
            #pragma unroll
            for (int dx = 0; dx < 9; ++dx)
                #pragma unroll
                for (int p = 0; p < 4; ++p)
                    acc[d][dx][p] = fmaf(fa[p], w[dx + p], acc[d][dx][p]);
        }

        if (hn) {
            *(float4*)&lds[1 - cur][lo0] = n0;
            if (s1ok) *(float4*)&lds[1 - cur][lo1] = n1;
        }
        __syncthreads();
    }

    // ---- epilogue ----
    const float invc = 1.0f / (float)Cn;
    float* ob = out + (size_t)b * 81 * CHS + (y0 + ty) * Wn + x0 + tx * 4;
    #pragma unroll
    for (int d = 0; d < 3; ++d) {
        #pragma unroll
        for (int dx = 0; dx < 9; ++dx) {
            const int chn = (3 * g + d) * 9 + dx;
            float4 o = make_float4(acc[d][dx][0] * invc,
                                   acc[d][dx][1] * invc,
                                   acc[d][dx][2] * invc,
                                   acc[d][dx][3] * invc);
            *(float4*)(ob + chn * CHS) = o;
        }
    }
}

extern "C" void kernel_launch(void* const* d_in, const int* in_sizes, int n_in,
                              void* d_out, int out_size, void* d_ws, size_t ws_size,
                              hipStream_t stream) {
    const float* first  = (const float*)d_in[0];
    const float* second = (const float*)d_in[1];
    float* out = (float*)d_out;

    dim3 grid(Wn / TW, Hn / TH, Bn * 3);   // (5, 6, 24) = 720 blocks
    corr3<<<grid, dim3(NT, 1, 1), 0, stream>>>(first, second, out);
}